// Round 1
// baseline (412.247 us; speedup 1.0000x reference)
//
#include <hip/hip_runtime.h>

#define N_NODES 100000
#define N_EDGES 1600000
#define F_IN    128
#define HID     16

// ---------------- degree count ----------------
__global__ __launch_bounds__(256) void deg_kernel(const int* __restrict__ row,
                                                  float* __restrict__ deg, int E) {
    int i = blockIdx.x * 256 + threadIdx.x;
    if (i < E) atomicAdd(&deg[row[i]], 1.0f);
}

// deg -> dinv in place
__global__ __launch_bounds__(256) void dinv_kernel(float* __restrict__ deg, int n) {
    int i = blockIdx.x * 256 + threadIdx.x;
    if (i < n) {
        float d = deg[i];
        deg[i] = d > 0.f ? 1.0f / sqrtf(d) : 0.f;
    }
}

// ---------------- layer1 projection: P0 = x@W1[0], P1 = x@W1[1] ----------------
// block = 256 threads, 8 nodes/block. LDS-stage 8 rows of x (128 f32 each).
// Each thread computes one of 32 outputs (16 for P0, 16 for P1) for one node.
__global__ __launch_bounds__(256) void proj1_kernel(const float* __restrict__ x,
                                                    const float* __restrict__ W1,
                                                    float* __restrict__ P0,
                                                    float* __restrict__ P1, int n) {
    __shared__ float lds[8 * 128];
    int base = blockIdx.x * 8;
    int t = threadIdx.x;
    for (int idx = t; idx < 8 * 128; idx += 256) {
        int nd = base + (idx >> 7);
        lds[idx] = (nd < n) ? x[(size_t)nd * 128 + (idx & 127)] : 0.f;
    }
    __syncthreads();
    int nl = t >> 5;     // node within block, 0..7
    int j  = t & 31;     // output index, 0..31
    int node = base + nl;
    if (node >= n) return;
    const float* w  = W1 + (j < 16 ? 0 : 2048) + (j & 15);  // W1 is (2,128,16)
    const float* xr = lds + nl * 128;
    float acc = 0.f;
#pragma unroll
    for (int k = 0; k < 128; ++k) acc += xr[k] * w[k * 16];
    if (j < 16) P0[(size_t)node * 16 + j]        = acc;
    else        P1[(size_t)node * 16 + (j - 16)] = acc;
}

// ---------------- edge aggregation: AGG[row] += P[col] * (-dinv[r]*dinv[c]) ----------------
// one thread per (edge, feature); 16 consecutive lanes share an edge.
__global__ __launch_bounds__(256) void agg_kernel(const int* __restrict__ row,
                                                  const int* __restrict__ col,
                                                  const float* __restrict__ dinv,
                                                  const float* __restrict__ P,
                                                  float* __restrict__ AGG, int E) {
    int tid = blockIdx.x * 256 + threadIdx.x;
    int e = tid >> 4;
    if (e >= E) return;
    int f = tid & 15;
    int r = row[e], c = col[e];
    float w = -dinv[r] * dinv[c];
    if (w != 0.f) {
        float v = P[(size_t)c * 16 + f] * w;
        atomicAdd(&AGG[(size_t)r * 16 + f], v);
    }
}

// ---------------- h = relu(P0 + AGG + b1), in place into P0 ----------------
__global__ __launch_bounds__(256) void relu_kernel(float* __restrict__ P0,
                                                   const float* __restrict__ AGG,
                                                   const float* __restrict__ b1, int total) {
    int i = blockIdx.x * 256 + threadIdx.x;
    if (i < total) {
        float v = P0[i] + AGG[i] + b1[i & 15];
        P0[i] = v > 0.f ? v : 0.f;
    }
}

// ---------------- out = log_softmax(H@W2[0] + AGG@W2[1] + b2) ----------------
// one wave (64 lanes) per node; each lane computes outputs j=lane and j=lane+64.
__global__ __launch_bounds__(256) void out_kernel(const float* __restrict__ H,
                                                  const float* __restrict__ AGG,
                                                  const float* __restrict__ W2,
                                                  const float* __restrict__ b2,
                                                  float* __restrict__ out, int n) {
    int wave = threadIdx.x >> 6;
    int lane = threadIdx.x & 63;
    int node = blockIdx.x * 4 + wave;
    if (node >= n) return;
    const float* h = H + (size_t)node * 16;
    const float* a = AGG + (size_t)node * 16;
    float o0 = b2[lane];
    float o1 = b2[lane + 64];
#pragma unroll
    for (int k = 0; k < 16; ++k) {
        float hv = h[k], av = a[k];
        o0 += hv * W2[k * 128 + lane]      + av * W2[2048 + k * 128 + lane];
        o1 += hv * W2[k * 128 + lane + 64] + av * W2[2048 + k * 128 + lane + 64];
    }
    // log-softmax over the 128 outputs (2 per lane)
    float m = fmaxf(o0, o1);
#pragma unroll
    for (int s = 1; s < 64; s <<= 1) m = fmaxf(m, __shfl_xor(m, s));
    float ssum = expf(o0 - m) + expf(o1 - m);
#pragma unroll
    for (int s = 1; s < 64; s <<= 1) ssum += __shfl_xor(ssum, s);
    float lse = m + logf(ssum);
    out[(size_t)node * 128 + lane]      = o0 - lse;
    out[(size_t)node * 128 + lane + 64] = o1 - lse;
}

extern "C" void kernel_launch(void* const* d_in, const int* in_sizes, int n_in,
                              void* d_out, int out_size, void* d_ws, size_t ws_size,
                              hipStream_t stream) {
    const float* x  = (const float*)d_in[0];
    const int*   ei = (const int*)d_in[1];
    const float* W1 = (const float*)d_in[2];
    const float* b1 = (const float*)d_in[3];
    const float* W2 = (const float*)d_in[4];
    const float* b2 = (const float*)d_in[5];
    float* out = (float*)d_out;

    const int n = N_NODES, E = N_EDGES;
    const int* row = ei;        // edge_index[0]
    const int* col = ei + E;    // edge_index[1]

    // workspace layout (float offsets)
    float* ws = (float*)d_ws;
    const size_t nPad = 100096;                 // N rounded up to 128
    float* deg = ws;                            // N floats (becomes dinv)
    float* P0  = ws + nPad;                     // N*16
    float* P1  = P0 + (size_t)n * 16;           // N*16
    float* AGG = P1 + (size_t)n * 16;           // N*16

    hipMemsetAsync(deg, 0, (size_t)n * sizeof(float), stream);
    hipMemsetAsync(AGG, 0, (size_t)n * 16 * sizeof(float), stream);

    deg_kernel<<<(E + 255) / 256, 256, 0, stream>>>(row, deg, E);
    dinv_kernel<<<(n + 255) / 256, 256, 0, stream>>>(deg, n);
    proj1_kernel<<<(n + 7) / 8, 256, 0, stream>>>(x, W1, P0, P1, n);
    agg_kernel<<<((size_t)E * 16 + 255) / 256, 256, 0, stream>>>(row, col, deg, P1, AGG, E);
    relu_kernel<<<(n * 16 + 255) / 256, 256, 0, stream>>>(P0, AGG, b1, n * 16);
    hipMemsetAsync(AGG, 0, (size_t)n * 16 * sizeof(float), stream);
    agg_kernel<<<((size_t)E * 16 + 255) / 256, 256, 0, stream>>>(row, col, deg, P0, AGG, E);
    out_kernel<<<(n + 3) / 4, 256, 0, stream>>>(P0, AGG, W2, b2, out, n);
}